// Round 3
// baseline (10620.194 us; speedup 1.0000x reference)
//
#include <hip/hip_runtime.h>
#include <hip/hip_bf16.h>

typedef __bf16 bf16x8 __attribute__((ext_vector_type(8)));
typedef float  f32x4  __attribute__((ext_vector_type(4)));

#define LR_C 0.001f
#define VMCNT(n) asm volatile("s_waitcnt vmcnt(" #n ")" ::: "memory")

__device__ __forceinline__ float sigf(float x){ return 1.0f/(1.0f + __expf(-x)); }

__device__ __forceinline__ void gload_lds16(const void* g, void* l){
  __builtin_amdgcn_global_load_lds(
      (const __attribute__((address_space(1))) void*)g,
      (__attribute__((address_space(3))) void*)l, 16, 0, 0);
}

// ---------------- prep kernels (once per launch) ----------------

__global__ void k_cvt_bf16(__hip_bfloat16* dst, const float* src, int n){
  int i = blockIdx.x*256 + threadIdx.x;
  if (i < n) dst[i] = __float2bfloat16(src[i]);
}

__global__ void k_cvt_pad(__hip_bfloat16* dst, const float* src, int rows, int cs, int cd){
  int i = blockIdx.x*256 + threadIdx.x;
  if (i >= rows*cd) return;
  int r = i / cd, c = i % cd;
  float v = (c < cs) ? src[r*cs + c] : 0.0f;
  dst[i] = __float2bfloat16(v);
}

// dst[n][j] (n<sc, stride dstride, j>=sr zero-padded) = src[j][n]
__global__ void k_transpose(__hip_bfloat16* dst, const float* src, int sr, int sc, int dstride){
  int i = blockIdx.x*256 + threadIdx.x;
  if (i >= sc*dstride) return;
  int n = i / dstride, j = i % dstride;
  float v = (j < sr) ? src[j*sc + n] : 0.0f;
  dst[i] = __float2bfloat16(v);
}

__global__ void k_init_state(float* sf, __hip_bfloat16* A, const float* s, int n){
  int i = blockIdx.x*256 + threadIdx.x;
  if (i >= n) return;
  float v = s[i];
  sf[i] = v;
  A[i] = __float2bfloat16(sigf(v));
}

// s3: 8192x10 -> s3f (stride 10), A3 (stride 64, cols 10..63 = 0)
__global__ void k_init_s3(float* s3f, __hip_bfloat16* A3, const float* s3){
  int i = blockIdx.x*256 + threadIdx.x;
  if (i >= 8192*64) return;
  int b = i >> 6, c = i & 63;
  if (c < 10){
    float v = s3[b*10 + c];
    s3f[b*10 + c] = v;
    A3[i] = __float2bfloat16(sigf(v));
  } else {
    A3[i] = __float2bfloat16(0.0f);
  }
}

__global__ void k_zero_bf16(__hip_bfloat16* p, int n){
  int i = blockIdx.x*256 + threadIdx.x;
  if (i < n) p[i] = __float2bfloat16(0.0f);
}

__global__ void k_copy_f32(float* dst, const float* src, int n){
  int i = blockIdx.x*256 + threadIdx.x;
  if (i < n) dst[i] = src[i];
}

// ---------------- 256x256 / BK=64 / 8-wave fused NT GEMM ----------------
// C = A(MxK,bf16) * B(NxK,bf16)^T ; K % 64 == 0 ; M % 256 == 0
// EP==0 (PRED): e = f_in - acc -> bf_out ; if f_out: f_out = acc
// EP==1 (UPD):  s=f_in; a=sig(s); sn = s + LR*(-e_in + a*(1-a)*acc)
// EP==2 (UPD3): same without -e term.

struct Op {
  const ushort* A; const ushort* B;
  int N, K, lda, ldb;
  const float* f_in; int fi;
  float* f_out; int fo;
  const __hip_bfloat16* e_in; int es;
  __hip_bfloat16* bf_out; int bfo;
  int nbx;
};

template<int EP>
__device__ __forceinline__ void gemm256(const Op& o, int lid, char* AsB, char* BsB){
  const int bx = lid % o.nbx;
  const int by = lid / o.nbx;
  const int brow = by * 256;
  const int bcol = bx * 256;

  const int t  = threadIdx.x;
  const int w  = t >> 6;          // wave 0..7
  const int l  = t & 63;
  const int wr = (w >> 2) * 128;  // 2 waves in M
  const int wc = (w & 3) * 64;    // 4 waves in N
  const int fr = l & 15;
  const int ks2  = ((l >> 4) * 8) * 2;       // k-slice byte offset
  const int swz  = ((l >> 2) & 1) << 5;      // st_16x32: row-bit2 -> byte-bit5
  const int rdks = ks2 ^ swz;

  f32x4 acc[8][4];
#pragma unroll
  for (int m=0;m<8;m++)
#pragma unroll
    for (int n=0;n<4;n++){ acc[m][n][0]=0.f; acc[m][n][1]=0.f; acc[m][n][2]=0.f; acc[m][n][3]=0.f; }

  // ---- staging: LDS linear, global source inverse-swizzled (rule #21) ----
  const int srow  = w*8 + (l>>3);                       // + q*64
  const int scolb = ((l&7)*16) ^ ((l>>5) << 5);         // swzbit(row)=((row>>2)&1)<<5 == (l>>5)&1
  const char* aSrc[4]; const char* bSrc[4];
#pragma unroll
  for (int q=0;q<4;q++){
    aSrc[q] = (const char*)o.A + (size_t)(brow + srow + q*64) * (size_t)(o.lda*2) + scolb;
    bSrc[q] = (const char*)o.B + (size_t)(bcol + srow + q*64) * (size_t)(o.ldb*2) + scolb;
  }
  char* aDst = AsB + w*1024;   // wave-uniform
  char* bDst = BsB + w*1024;

  auto STAGE = [&](int buf, int tk){
    const size_t ko = (size_t)tk * 128;   // 64 cols * 2B
#pragma unroll
    for (int q=0;q<4;q++) gload_lds16(aSrc[q]+ko, aDst + buf*32768 + q*8192);
#pragma unroll
    for (int q=0;q<4;q++) gload_lds16(bSrc[q]+ko, bDst + buf*32768 + q*8192);
  };

  // ---- swizzled ds_read offsets ----
  int offA[8], offB[4];
#pragma unroll
  for (int m=0;m<8;m++) offA[m] = (wr + m*16 + fr)*128 + rdks;
#pragma unroll
  for (int n=0;n<4;n++) offB[n] = (wc + n*16 + fr)*128 + rdks;

  const int nt = o.K >> 6;
  STAGE(0,0);
  if (nt > 1) STAGE(1,1);

  for (int tk=0; tk<nt; ++tk){
    const int cur = tk & 1;
    if (tk+1 < nt) { VMCNT(8); } else { VMCNT(0); }   // counted: next tile stays in flight
    __builtin_amdgcn_s_barrier();
    const char* Ab = AsB + cur*32768;
    const char* Bb = BsB + cur*32768;
    __builtin_amdgcn_s_setprio(1);
    bf16x8 bfr[4], afr[4];
    // phase 1: kk=0, m 0..3
#pragma unroll
    for (int n=0;n<4;n++) bfr[n] = *(const bf16x8*)(Bb + offB[n]);
#pragma unroll
    for (int i=0;i<4;i++) afr[i] = *(const bf16x8*)(Ab + offA[i]);
#pragma unroll
    for (int i=0;i<4;i++)
#pragma unroll
      for (int n=0;n<4;n++)
        acc[i][n] = __builtin_amdgcn_mfma_f32_16x16x32_bf16(afr[i], bfr[n], acc[i][n], 0,0,0);
    // phase 2: kk=0, m 4..7
#pragma unroll
    for (int i=0;i<4;i++) afr[i] = *(const bf16x8*)(Ab + offA[4+i]);
#pragma unroll
    for (int i=0;i<4;i++)
#pragma unroll
      for (int n=0;n<4;n++)
        acc[4+i][n] = __builtin_amdgcn_mfma_f32_16x16x32_bf16(afr[i], bfr[n], acc[4+i][n], 0,0,0);
    // phase 3: kk=1, m 0..3
#pragma unroll
    for (int n=0;n<4;n++) bfr[n] = *(const bf16x8*)(Bb + offB[n] + 64);
#pragma unroll
    for (int i=0;i<4;i++) afr[i] = *(const bf16x8*)(Ab + offA[i] + 64);
#pragma unroll
    for (int i=0;i<4;i++)
#pragma unroll
      for (int n=0;n<4;n++)
        acc[i][n] = __builtin_amdgcn_mfma_f32_16x16x32_bf16(afr[i], bfr[n], acc[i][n], 0,0,0);
    // phase 4: kk=1, m 4..7
#pragma unroll
    for (int i=0;i<4;i++) afr[i] = *(const bf16x8*)(Ab + offA[4+i] + 64);
#pragma unroll
    for (int i=0;i<4;i++)
#pragma unroll
      for (int n=0;n<4;n++)
        acc[4+i][n] = __builtin_amdgcn_mfma_f32_16x16x32_bf16(afr[i], bfr[n], acc[4+i][n], 0,0,0);
    __builtin_amdgcn_s_setprio(0);
    __builtin_amdgcn_s_barrier();                    // all waves done reading buf[cur]
    if (tk+2 < nt) STAGE(cur, tk+2);                 // refill behind the barrier
  }

  // ---- epilogue ----
  const int orow0 = brow + wr + ((l>>4) * 4);
  const int ocol0 = bcol + wc + fr;
#pragma unroll
  for (int m=0;m<8;m++){
#pragma unroll
    for (int n=0;n<4;n++){
      int col = ocol0 + n*16;
      if (col >= o.N) continue;
#pragma unroll
      for (int j=0;j<4;j++){
        int row = orow0 + m*16 + j;
        float g = acc[m][n][j];
        if (EP == 0){
          float e = o.f_in[(size_t)row*o.fi + col] - g;
          o.bf_out[(size_t)row*o.bfo + col] = __float2bfloat16(e);
          if (o.f_out) o.f_out[(size_t)row*o.fo + col] = g;
        } else {
          float s = o.f_in[(size_t)row*o.fi + col];
          float a = sigf(s);
          float upd = a*(1.0f-a)*g;
          if (EP == 1) upd -= __bfloat162float(o.e_in[(size_t)row*o.es + col]);
          float sn = s + LR_C*upd;
          o.f_out[(size_t)row*o.fo + col] = sn;
          o.bf_out[(size_t)row*o.bfo + col] = __float2bfloat16(sigf(sn));
        }
      }
    }
  }
}

template<int EPa,int EPb,int EPc>
__global__ __launch_bounds__(512,2)
void fused3(Op oa, Op ob, Op oc, int na, int nab){
  __shared__ __align__(16) char lds[131072];
  char* AsB = lds;
  char* BsB = lds + 65536;
  int bid = blockIdx.x;
  if (bid < na)       gemm256<EPa>(oa, bid,       AsB, BsB);
  else if (bid < nab) gemm256<EPb>(ob, bid - na,  AsB, BsB);
  else                gemm256<EPc>(oc, bid - nab, AsB, BsB);
}

// ---------------- host orchestration ----------------

extern "C" void kernel_launch(void* const* d_in, const int* in_sizes, int n_in,
                              void* d_out, int out_size, void* d_ws, size_t ws_size,
                              hipStream_t stream) {
  const float* input = (const float*)d_in[0];
  const float* s1    = (const float*)d_in[1];
  const float* s2    = (const float*)d_in[2];
  const float* s3    = (const float*)d_in[3];
  const float* W1    = (const float*)d_in[4];
  const float* W2    = (const float*)d_in[5];
  const float* W3    = (const float*)d_in[6];
  float* out = (float*)d_out;

  char* ws = (char*)d_ws;
  size_t off = 0;
  auto take = [&](size_t bytes)->char*{
    char* p = ws + off;
    off = (off + bytes + 255) & ~(size_t)255;
    return p;
  };

  float* s1f = (float*)take(8192ull*1024*4);
  float* s2f = (float*)take(8192ull*512*4);
  float* s3f = (float*)take(8192ull*10*4);
  __hip_bfloat16* A1  = (__hip_bfloat16*)take(8192ull*1024*2);
  __hip_bfloat16* A2  = (__hip_bfloat16*)take(8192ull*512*2);
  __hip_bfloat16* A3  = (__hip_bfloat16*)take(8192ull*64*2);    // K 10->64 padded
  __hip_bfloat16* e0  = (__hip_bfloat16*)take(8192ull*832*2);   // K 784->832 padded
  __hip_bfloat16* e1  = (__hip_bfloat16*)take(8192ull*1024*2);
  __hip_bfloat16* e2  = (__hip_bfloat16*)take(8192ull*512*2);
  __hip_bfloat16* W1b = (__hip_bfloat16*)take(1024ull*1024*2);  // N 784->1024 padded rows
  __hip_bfloat16* W2b = (__hip_bfloat16*)take(1024ull*512*2);
  __hip_bfloat16* W3b = (__hip_bfloat16*)take(512ull*64*2);     // K 10->64 padded
  __hip_bfloat16* W1T = (__hip_bfloat16*)take(1024ull*832*2);   // K 784->832 padded
  __hip_bfloat16* W2T = (__hip_bfloat16*)take(512ull*1024*2);
  __hip_bfloat16* W3T = (__hip_bfloat16*)take(256ull*512*2);    // N 10->256 padded rows

  auto cdiv = [](int a, int b){ return (a + b - 1) / b; };

  // --- prep ---
  k_zero_bf16<<<cdiv(1024*1024,256),256,0,stream>>>(W1b, 1024*1024);
  k_cvt_bf16 <<<cdiv(784*1024,256),256,0,stream>>>(W1b, W1, 784*1024);
  k_cvt_bf16 <<<cdiv(1024*512,256),256,0,stream>>>(W2b, W2, 1024*512);
  k_cvt_pad  <<<cdiv(512*64,256),256,0,stream>>>(W3b, W3, 512, 10, 64);
  k_transpose<<<cdiv(1024*832,256),256,0,stream>>>(W1T, W1, 784, 1024, 832);
  k_transpose<<<cdiv(512*1024,256),256,0,stream>>>(W2T, W2, 1024, 512, 1024);
  k_zero_bf16<<<cdiv(256*512,256),256,0,stream>>>(W3T, 256*512);
  k_transpose<<<cdiv(10*512,256),256,0,stream>>>(W3T, W3, 512, 10, 512);
  k_init_state<<<cdiv(8192*1024,256),256,0,stream>>>(s1f, A1, s1, 8192*1024);
  k_init_state<<<cdiv(8192*512,256),256,0,stream>>>(s2f, A2, s2, 8192*512);
  k_init_s3  <<<cdiv(8192*64,256),256,0,stream>>>(s3f, A3, s3);
  k_zero_bf16<<<cdiv(8192*832,256),256,0,stream>>>(e0, 8192*832);

  // --- Op descriptors ---
  Op P1{(const ushort*)A1, (const ushort*)W1b, 784, 1024, 1024, 1024,
        input, 784, nullptr, 784, nullptr, 0, e0, 832, 4};
  Op P2{(const ushort*)A2, (const ushort*)W2b, 1024, 512, 512, 512,
        s1f, 1024, nullptr, 0, nullptr, 0, e1, 1024, 4};
  Op P3{(const ushort*)A3, (const ushort*)W3b, 512, 64, 64, 64,
        s2f, 512, nullptr, 0, nullptr, 0, e2, 512, 2};
  Op U1{(const ushort*)e0, (const ushort*)W1T, 1024, 832, 832, 832,
        s1f, 1024, s1f, 1024, e1, 1024, A1, 1024, 4};
  Op U2{(const ushort*)e1, (const ushort*)W2T, 512, 1024, 1024, 1024,
        s2f, 512, s2f, 512, e2, 512, A2, 512, 2};
  Op U3{(const ushort*)e2, (const ushort*)W3T, 10, 512, 512, 512,
        s3f, 10, s3f, 10, nullptr, 0, A3, 64, 1};

  const int nP1 = 4*32, nP2 = 4*32, nP3 = 2*32;   // 128,128,64 -> 320
  const int nU1 = 4*32, nU2 = 2*32, nU3 = 1*32;   // 128,64,32  -> 224

  for (int c = 0; c < 60; ++c){
    P1.f_out = (c == 59) ? (out + 8192*10) : nullptr;
    fused3<0,0,0><<<nP1+nP2+nP3, 512, 0, stream>>>(P1, P2, P3, nP1, nP1+nP2);
    fused3<1,1,2><<<nU1+nU2+nU3, 512, 0, stream>>>(U1, U2, U3, nU1, nU1+nU2);
  }

  k_copy_f32<<<cdiv(8192*10,256),256,0,stream>>>(out, s3f, 8192*10);
}